// Round 4
// baseline (227.493 us; speedup 1.0000x reference)
//
#include <hip/hip_runtime.h>

// Problem constants
constexpr int Bc = 256;   // batch
constexpr int Nc = 512;   // nodes
constexpr int Dc = 256;   // dim_graph == dim_desc
constexpr int Rc = 64;    // rank
constexpr int SPLIT = 8;  // N-splits per b in the hot kernel
constexpr int ROWS = Nc / SPLIT;   // 64 rows per k1 block
constexpr int GROUP = 32;          // rows per A/B pass group (32 KB, L1-resident)

// Workspace layout (floats)
constexpr size_t WS_P = 0;                       // p[B][D]         : 65536
constexpr size_t WS_L = WS_P + (size_t)Bc * Dc;  // l_part[B][S]    : 2048
constexpr size_t WS_H = WS_L + (size_t)Bc * SPLIT;            // h_part[B][S][D] : 524288
constexpr size_t WS_FLOATS = WS_H + (size_t)Bc * SPLIT * Dc;  // total 591872

// ---------------------------------------------------------------- kernel 0
// p[b][d] = sum_r (tokns_k[b]·Wq[r]) * Wk[r][d]
__global__ __launch_bounds__(256) void k0_precompute_p(
    const float* __restrict__ tokns_k, const float* __restrict__ Wq,
    const float* __restrict__ Wk, float* __restrict__ ws)
{
    const int b = blockIdx.x;
    const int t = threadIdx.x;
    const int wave = t >> 6, lane = t & 63, g = lane >> 4, l16 = lane & 15;

    __shared__ float q_s[Rc];

    #pragma unroll
    for (int step = 0; step < 4; ++step) {
        const int r = wave * 16 + step * 4 + g;
        float acc = 0.0f;
        #pragma unroll
        for (int j = 0; j < 4; ++j) {
            const float4 tk = *(const float4*)(tokns_k + b * Dc + l16 * 4 + j * 64);
            const float4 wq = *(const float4*)(Wq + r * Dc + l16 * 4 + j * 64);
            acc += tk.x * wq.x + tk.y * wq.y + tk.z * wq.z + tk.w * wq.w;
        }
        #pragma unroll
        for (int off = 1; off < 16; off <<= 1) acc += __shfl_xor(acc, off);
        if (l16 == 0) q_s[r] = acc;
    }
    __syncthreads();

    float acc = 0.0f;
    #pragma unroll 8
    for (int r = 0; r < Rc; ++r) acc += q_s[r] * Wk[r * Dc + t];
    ws[WS_P + (size_t)b * Dc + t] = acc;
}

// ---------------------------------------------------------------- kernel 1
// Two-pass per 32-row group:
//   Pass A: 8-lane row-teams compute scores (3 shuffles/row), pn -> LDS.
//   Pass B: 16-lane col-teams accumulate h += pn*x, ZERO shuffles (L1-hot re-read).
__global__ __launch_bounds__(256) void k1_stream(
    const float* __restrict__ H_pad, const int* __restrict__ mask,
    const float* __restrict__ log_scale, float* __restrict__ ws,
    float* __restrict__ out)
{
    const int s = blockIdx.x;    // split
    const int b = blockIdx.y;    // batch
    const int t = threadIdx.x;
    const int n0 = s * ROWS;

    // Pass A identity: 8-lane teams, one row each (32 rows per group)
    const int rowA = t >> 3;     // 0..31 (row within group)
    const int e    = t & 7;      // lane within row team
    // Pass B identity: 16-lane col-teams
    const int tau  = t >> 4;     // 0..15 team
    const int l16  = t & 15;

    __shared__ __align__(16) float hm[16][Dc];   // 16 team partials, 16 KB
    __shared__ float pn_s[ROWS];                 // exp(score) per row
    __shared__ float scores_s[ROWS];
    __shared__ int   mask_s[ROWS];

    if (t < ROWS) mask_s[t] = mask[b * Nc + n0 + t];

    const float inv_scale = 1.0f / fmaxf(__expf(log_scale[0]), 0.1f);

    // Pass-A p fragment: float4 chunks (e + 8k), k=0..7 -> 32 floats in regs
    const float* __restrict__ pb = ws + WS_P + (size_t)b * Dc;
    float4 pA[8];
    #pragma unroll
    for (int k = 0; k < 8; ++k) pA[k] = *(const float4*)(pb + (e + 8 * k) * 4);

    const float* __restrict__ Hb = H_pad + ((size_t)b * Nc + n0) * Dc;

    float4 h4[4];
    #pragma unroll
    for (int j = 0; j < 4; ++j) h4[j] = make_float4(0.f, 0.f, 0.f, 0.f);

    __syncthreads();   // mask_s ready

    #pragma unroll
    for (int g = 0; g < ROWS / GROUP; ++g) {
        // ---- Pass A: scores for rows [g*32, g*32+32)
        {
            const int n = g * GROUP + rowA;
            const float* __restrict__ row = Hb + n * Dc;
            float4 x[8];
            #pragma unroll
            for (int k = 0; k < 8; ++k) x[k] = *(const float4*)(row + (e + 8 * k) * 4);
            float acc = 0.0f;
            #pragma unroll
            for (int k = 0; k < 8; ++k)
                acc += x[k].x * pA[k].x + x[k].y * pA[k].y
                     + x[k].z * pA[k].z + x[k].w * pA[k].w;
            acc += __shfl_xor(acc, 1);
            acc += __shfl_xor(acc, 2);
            acc += __shfl_xor(acc, 4);
            acc *= inv_scale;
            if (mask_s[n] == 0) acc = -1e30f;   // exp underflows to exact 0
            if (e == 0) {
                scores_s[n] = acc;
                pn_s[n] = __expf(acc);          // |scores| << 88 (validated R2/R3)
            }
        }
        __syncthreads();   // pn ready for this group

        // ---- Pass B: h += pn * x over the same rows (L1-hot), no shuffles
        #pragma unroll
        for (int r = 0; r < 2; ++r) {
            const int n = g * GROUP + tau * 2 + r;
            const float pn = pn_s[n];           // LDS broadcast
            const float* __restrict__ row = Hb + n * Dc;
            #pragma unroll
            for (int j = 0; j < 4; ++j) {
                const float4 x = *(const float4*)(row + (l16 + 16 * j) * 4);
                h4[j].x = fmaf(pn, x.x, h4[j].x);
                h4[j].y = fmaf(pn, x.y, h4[j].y);
                h4[j].z = fmaf(pn, x.z, h4[j].z);
                h4[j].w = fmaf(pn, x.w, h4[j].w);
            }
        }
        // no barrier needed: next Pass A writes pn_s[other group's rows] (disjoint)
    }

    // publish 16 team partials
    #pragma unroll
    for (int j = 0; j < 4; ++j) *(float4*)(&hm[tau][(l16 + 16 * j) * 4]) = h4[j];
    __syncthreads();

    // raw scores out (k2 normalizes); L partial via wave-0 butterfly
    if (t < ROWS) out[b * Nc + n0 + t] = scores_s[t];
    if (t < ROWS) {
        float L = pn_s[t];
        #pragma unroll
        for (int off = 32; off >= 1; off >>= 1) L += __shfl_xor(L, off);
        if (t == 0) ws[WS_L + (size_t)b * SPLIT + s] = L;
    }
    float hsum = 0.0f;
    #pragma unroll
    for (int p = 0; p < 16; ++p) hsum += hm[p][t];
    ws[WS_H + ((size_t)b * SPLIT + s) * Dc + t] = hsum;
}

// ---------------------------------------------------------------- kernel 2
// Merge partials: normalize alpha in-place, hbar, ctx = hbar @ Wv^T.
__global__ __launch_bounds__(256) void k2_merge(
    const float* __restrict__ Wv, const float* __restrict__ ws,
    float* __restrict__ out)
{
    const int b = blockIdx.x;
    const int t = threadIdx.x;
    const int wave = t >> 6, lane = t & 63, g = lane >> 4, l16 = lane & 15;

    __shared__ __align__(16) float hbar[Dc];

    float L = 0.0f;
    #pragma unroll
    for (int s = 0; s < SPLIT; ++s) L += ws[WS_L + (size_t)b * SPLIT + s];
    const float invL = 1.0f / L;

    float hacc = 0.0f;
    #pragma unroll
    for (int s = 0; s < SPLIT; ++s) hacc += ws[WS_H + ((size_t)b * SPLIT + s) * Dc + t];
    hbar[t] = hacc * invL;

    // normalize alpha in place (raw scores were written by k1)
    #pragma unroll
    for (int i = 0; i < Nc / 256; ++i) {
        const int idx = b * Nc + i * 256 + t;
        out[idx] = __expf(out[idx]) * invL;
    }
    __syncthreads();

    float4 hb4[4];
    #pragma unroll
    for (int j = 0; j < 4; ++j) hb4[j] = *(const float4*)(hbar + l16 * 4 + j * 64);
    float* __restrict__ ctx_out = out + (size_t)Bc * Nc + b * Dc;
    #pragma unroll
    for (int step = 0; step < 16; ++step) {
        const int e = step * 16 + wave * 4 + g;
        float acc = 0.0f;
        #pragma unroll
        for (int j = 0; j < 4; ++j) {
            const float4 wv = *(const float4*)(Wv + e * Dc + l16 * 4 + j * 64);
            acc += wv.x * hb4[j].x + wv.y * hb4[j].y + wv.z * hb4[j].z + wv.w * hb4[j].w;
        }
        #pragma unroll
        for (int off = 1; off < 16; off <<= 1) acc += __shfl_xor(acc, off);
        if (l16 == 0) ctx_out[e] = acc;
    }
}

// ---------------------------------------------------------------- fallback
// Round-2 single-kernel version (passed validation) for small ws_size.
constexpr int FNT = 512;
constexpr int FNW = FNT / 64;
constexpr int FNPW = Nc / FNW;

__global__ __launch_bounds__(FNT) void fba_fallback(
    const float* __restrict__ tokns_k, const float* __restrict__ H_pad,
    const int* __restrict__ mask, const float* __restrict__ Wq,
    const float* __restrict__ Wk, const float* __restrict__ Wv,
    const float* __restrict__ log_scale, float* __restrict__ out)
{
    const int b = blockIdx.x, t = threadIdx.x;
    const int wave = t >> 6, lane = t & 63;

    __shared__ __align__(16) float q_s[Rc];
    __shared__ __align__(16) float p_s[Dc];
    __shared__ __align__(16) float scores_s[Nc];
    __shared__ __align__(16) float hmerge[FNW][Dc];
    __shared__ float l_s[FNW];
    __shared__ __align__(16) float hbar[Dc];
    __shared__ int mask_s[Nc];

    const float inv_scale = 1.0f / fmaxf(__expf(log_scale[0]), 0.1f);

    const float4 tok4 = *(const float4*)(tokns_k + b * Dc + lane * 4);
    #pragma unroll
    for (int i = 0; i < Rc / FNW; ++i) {
        const int r = wave * (Rc / FNW) + i;
        const float4 w4 = *(const float4*)(Wq + r * Dc + lane * 4);
        float s = w4.x * tok4.x + w4.y * tok4.y + w4.z * tok4.z + w4.w * tok4.w;
        #pragma unroll
        for (int off = 32; off >= 1; off >>= 1) s += __shfl_xor(s, off);
        if (lane == 0) q_s[r] = s;
    }
    mask_s[t] = mask[b * Nc + t];
    mask_s[t + FNT] = mask[b * Nc + t + FNT];
    __syncthreads();

    if (t < Dc) {
        float acc = 0.0f;
        #pragma unroll 8
        for (int r = 0; r < Rc; ++r) acc += q_s[r] * Wk[r * Dc + t];
        p_s[t] = acc;
    }
    __syncthreads();

    const float4 p4 = *(const float4*)(p_s + lane * 4);
    const float* Hb = H_pad + (size_t)b * Nc * Dc;
    float l_acc = 0.0f;
    float4 h4 = make_float4(0.f, 0.f, 0.f, 0.f);

    for (int i = 0; i < FNPW; ++i) {
        const int n = wave * FNPW + i;
        const float4 x4 = *(const float4*)(Hb + n * Dc + lane * 4);
        float s = x4.x * p4.x + x4.y * p4.y + x4.z * p4.z + x4.w * p4.w;
        #pragma unroll
        for (int off = 32; off >= 1; off >>= 1) s += __shfl_xor(s, off);
        s *= inv_scale;
        if (mask_s[n] == 0) s = -1e30f;
        if (lane == 0) scores_s[n] = s;
        const float pn = __expf(s);
        l_acc += pn;
        h4.x = fmaf(pn, x4.x, h4.x); h4.y = fmaf(pn, x4.y, h4.y);
        h4.z = fmaf(pn, x4.z, h4.z); h4.w = fmaf(pn, x4.w, h4.w);
    }

    if (lane == 0) l_s[wave] = l_acc;
    *(float4*)(&hmerge[wave][lane * 4]) = h4;
    __syncthreads();

    float L = 0.0f;
    #pragma unroll
    for (int w = 0; w < FNW; ++w) L += l_s[w];
    const float invL = 1.0f / L;

    if (t < Dc) {
        float acc = 0.0f;
        #pragma unroll
        for (int w = 0; w < FNW; ++w) acc += hmerge[w][t];
        hbar[t] = acc * invL;
    }
    out[b * Nc + t] = __expf(scores_s[t]) * invL;
    out[b * Nc + t + FNT] = __expf(scores_s[t + FNT]) * invL;
    __syncthreads();

    const float4 hb4 = *(const float4*)(hbar + lane * 4);
    float* ctx_out = out + (size_t)Bc * Nc + b * Dc;
    #pragma unroll
    for (int i = 0; i < Dc / FNW; ++i) {
        const int e = wave * (Dc / FNW) + i;
        const float4 w4 = *(const float4*)(Wv + e * Dc + lane * 4);
        float s = w4.x * hb4.x + w4.y * hb4.y + w4.z * hb4.z + w4.w * hb4.w;
        #pragma unroll
        for (int off = 32; off >= 1; off >>= 1) s += __shfl_xor(s, off);
        if (lane == 0) ctx_out[e] = s;
    }
}

extern "C" void kernel_launch(void* const* d_in, const int* in_sizes, int n_in,
                              void* d_out, int out_size, void* d_ws, size_t ws_size,
                              hipStream_t stream) {
    const float* tokns_k   = (const float*)d_in[0];
    const float* H_pad     = (const float*)d_in[1];
    const int*   mask      = (const int*)d_in[2];
    const float* Wq        = (const float*)d_in[3];
    const float* Wk        = (const float*)d_in[4];
    const float* Wv        = (const float*)d_in[5];
    const float* log_scale = (const float*)d_in[6];
    float* out = (float*)d_out;

    if (ws_size >= WS_FLOATS * sizeof(float)) {
        float* ws = (float*)d_ws;
        k0_precompute_p<<<Bc, 256, 0, stream>>>(tokns_k, Wq, Wk, ws);
        dim3 grid1(SPLIT, Bc);
        k1_stream<<<grid1, 256, 0, stream>>>(H_pad, mask, log_scale, ws, out);
        k2_merge<<<Bc, 256, 0, stream>>>(Wv, ws, out);
    } else {
        fba_fallback<<<Bc, FNT, 0, stream>>>(tokns_k, H_pad, mask, Wq, Wk, Wv,
                                             log_scale, out);
    }
}